// Round 1
// baseline (161.333 us; speedup 1.0000x reference)
//
#include <hip/hip_runtime.h>
#include <hip/hip_bf16.h>

#define NB 16
#define NN 512
#define ND 512
#define NH 8

using short8 = __attribute__((ext_vector_type(8))) short;
using f32x4  = __attribute__((ext_vector_type(4))) float;

static __device__ __forceinline__ unsigned short f2bf(float f) {
  unsigned u = __builtin_bit_cast(unsigned, f);
  unsigned r = 0x7fffu + ((u >> 16) & 1u);
  return (unsigned short)((u + r) >> 16);
}

// ---------------------------------------------------------------- kernel 0
// Transpose 4 weight mats [k][n] fp32 -> [n][k] bf16 (Wq,Wk,Wv,Wo)
__global__ __launch_bounds__(256) void wprep(
    const float* __restrict__ Wq, const float* __restrict__ Wk,
    const float* __restrict__ Wv, const float* __restrict__ Wo,
    unsigned short* __restrict__ T) {
  const float* W;
  switch (blockIdx.z) {
    case 0: W = Wq; break;
    case 1: W = Wk; break;
    case 2: W = Wv; break;
    default: W = Wo; break;
  }
  unsigned short* Wt = T + (size_t)blockIdx.z * 512 * 512;
  __shared__ float tile[64][65];
  const int t = threadIdx.x;
  const int k0 = blockIdx.x * 64, n0 = blockIdx.y * 64;
#pragma unroll
  for (int it = 0; it < 4; ++it) {
    int row = it * 16 + (t >> 4);
    int c4 = (t & 15) * 4;
    float4 v = *(const float4*)&W[(size_t)(k0 + row) * 512 + n0 + c4];
    tile[row][c4] = v.x; tile[row][c4 + 1] = v.y;
    tile[row][c4 + 2] = v.z; tile[row][c4 + 3] = v.w;
  }
  __syncthreads();
#pragma unroll
  for (int it = 0; it < 4; ++it) {
    int nr = it * 16 + (t >> 4);
    int k4 = (t & 15) * 4;
    ushort4 o;
    o.x = f2bf(tile[k4 + 0][nr]); o.y = f2bf(tile[k4 + 1][nr]);
    o.z = f2bf(tile[k4 + 2][nr]); o.w = f2bf(tile[k4 + 3][nr]);
    *(ushort4*)&Wt[(size_t)(n0 + nr) * 512 + k0 + k4] = o;
  }
}

// ---------------------------------------------------------------- kernel 1
// QKV projection: X[8192x512]fp32 @ Wt^T + b -> bf16, scattered to
// q_ws/k_ws [B,H,N,64], vt_ws [B,H,64,N]
__global__ __launch_bounds__(256) void qkv_gemm(
    const float* __restrict__ Xq, const float* __restrict__ Xk,
    const float* __restrict__ Xv, const unsigned short* __restrict__ Wt,
    const float* __restrict__ bq, const float* __restrict__ bk,
    const float* __restrict__ bv, unsigned short* __restrict__ q_ws,
    unsigned short* __restrict__ k_ws, unsigned short* __restrict__ vt_ws) {
  const int zi = blockIdx.z;
  const float* X = (zi == 0) ? Xq : (zi == 1) ? Xk : Xv;
  const unsigned short* Wz = Wt + (size_t)zi * 512 * 512;
  const float* bias = (zi == 0) ? bq : (zi == 1) ? bk : bv;
  const int m0 = blockIdx.x * 128, n0 = blockIdx.y * 128;
  __shared__ unsigned short Al[2][128][40];
  __shared__ unsigned short Bl[2][128][40];
  const int t = threadIdx.x;
  const int w = t >> 6, l = t & 63;
  const int lr = l & 15, lg = l >> 4;
  const int wr = (w >> 1) * 64, wc = (w & 1) * 64;
  f32x4 acc[4][4] = {};
  for (int kk = 0; kk < 512; kk += 64) {
    __syncthreads();
    {
      const int colk = (t & 15) * 4;
      const int kc = colk >> 5, kin = colk & 31;
#pragma unroll
      for (int p = 0; p < 8; ++p) {
        int row = p * 16 + (t >> 4);
        float4 v = *(const float4*)&X[(size_t)(m0 + row) * 512 + kk + colk];
        ushort4 o;
        o.x = f2bf(v.x); o.y = f2bf(v.y); o.z = f2bf(v.z); o.w = f2bf(v.w);
        *(ushort4*)&Al[kc][row][kin] = o;
      }
      const int colk8 = (t & 7) * 8;
      const int kc2 = colk8 >> 5, kin2 = colk8 & 31;
#pragma unroll
      for (int p = 0; p < 4; ++p) {
        int row = p * 32 + (t >> 3);
        short8 v = *(const short8*)&Wz[(size_t)(n0 + row) * 512 + kk + colk8];
        *(short8*)&Bl[kc2][row][kin2] = v;
      }
    }
    __syncthreads();
#pragma unroll
    for (int kc = 0; kc < 2; ++kc) {
      short8 a[4], b[4];
      const int lk = lg * 8;
#pragma unroll
      for (int i = 0; i < 4; ++i) a[i] = *(const short8*)&Al[kc][wr + i * 16 + lr][lk];
#pragma unroll
      for (int i = 0; i < 4; ++i) b[i] = *(const short8*)&Bl[kc][wc + i * 16 + lr][lk];
#pragma unroll
      for (int i = 0; i < 4; ++i)
#pragma unroll
        for (int j = 0; j < 4; ++j)
          acc[i][j] = __builtin_amdgcn_mfma_f32_16x16x32_bf16(a[i], b[j], acc[i][j], 0, 0, 0);
    }
  }
#pragma unroll
  for (int j = 0; j < 4; ++j) {
    const int col = n0 + wc + j * 16 + lr;
    const float bb = bias[col];
    const int hh = col >> 6, dv = col & 63;
#pragma unroll
    for (int i = 0; i < 4; ++i) {
      const int mbase = m0 + wr + i * 16 + lg * 4;
      const int b_ = mbase >> 9, nt = mbase & 511;
      if (zi == 2) {
        ushort4 o;
        o.x = f2bf(acc[i][j][0] + bb); o.y = f2bf(acc[i][j][1] + bb);
        o.z = f2bf(acc[i][j][2] + bb); o.w = f2bf(acc[i][j][3] + bb);
        *(ushort4*)&vt_ws[((size_t)(b_ * NH + hh) * 64 + dv) * 512 + nt] = o;
      } else {
        unsigned short* dst = (zi == 0) ? q_ws : k_ws;
#pragma unroll
        for (int r = 0; r < 4; ++r)
          dst[((size_t)(b_ * NH + hh) * 512 + nt + r) * 64 + dv] = f2bf(acc[i][j][r] + bb);
      }
    }
  }
}

// ---------------------------------------------------------------- kernel 2
// Attention: per block = 32 q-rows of one (b,h).
__global__ __launch_bounds__(256) void attn_kernel(
    const unsigned short* __restrict__ q_ws, const unsigned short* __restrict__ k_ws,
    const unsigned short* __restrict__ vt_ws, const float* __restrict__ box,
    const float* __restrict__ Ext, unsigned short* __restrict__ hidden) {
  const int t = threadIdx.x;
  const int w = t >> 6, l = t & 63;
  const int lr = l & 15, lg = l >> 4;
  const int bh = blockIdx.y;
  const int q0 = blockIdx.x * 32;
  const int b = bh >> 3, h = bh & 7;

  const unsigned short* Qp = q_ws + (size_t)bh * 512 * 64;
  const unsigned short* Kp = k_ws + (size_t)bh * 512 * 64;
  const unsigned short* Vt = vt_ws + (size_t)bh * 64 * 512;
  const float* boxp = box + (size_t)bh * 512 * 512;
  const float* Ep = Ext + (size_t)bh * 512 * 512;

  __shared__ float red[4][32];
  __shared__ float red2[4][32];
  __shared__ __align__(16) unsigned char wsh[4][8704];  // per-wave: P bf16 [32][136] == out f32 [32][68]

  // Q fragments (registers, reused for all 8 col-frags)
  short8 qf[2][2];
#pragma unroll
  for (int rg = 0; rg < 2; ++rg)
#pragma unroll
    for (int kc = 0; kc < 2; ++kc)
      qf[rg][kc] = *(const short8*)&Qp[(size_t)(q0 + rg * 16 + lr) * 64 + kc * 32 + lg * 8];

  // z = QK^T
  f32x4 z[2][8];
#pragma unroll
  for (int c = 0; c < 8; ++c) {
    const int n = w * 128 + c * 16;
    short8 kf0 = *(const short8*)&Kp[(size_t)(n + lr) * 64 + lg * 8];
    short8 kf1 = *(const short8*)&Kp[(size_t)(n + lr) * 64 + 32 + lg * 8];
#pragma unroll
    for (int rg = 0; rg < 2; ++rg) {
      f32x4 a = {0.f, 0.f, 0.f, 0.f};
      a = __builtin_amdgcn_mfma_f32_16x16x32_bf16(qf[rg][0], kf0, a, 0, 0, 0);
      a = __builtin_amdgcn_mfma_f32_16x16x32_bf16(qf[rg][1], kf1, a, 0, 0, 0);
      z[rg][c] = a;
    }
  }
  // logits = z*scale + log(clip(box))
#pragma unroll
  for (int rg = 0; rg < 2; ++rg)
#pragma unroll
    for (int c = 0; c < 8; ++c)
#pragma unroll
      for (int r = 0; r < 4; ++r) {
        const int row = q0 + rg * 16 + lg * 4 + r;
        const int col = w * 128 + c * 16 + lr;
        float bx = boxp[(size_t)row * 512 + col];
        z[rg][c][r] = z[rg][c][r] * 0.125f + __logf(fmaxf(bx, 1e-6f));
      }

  // ---- softmax 1: row max ----
  float m1[2][4];
  {
    float pm[2][4];
#pragma unroll
    for (int rg = 0; rg < 2; ++rg)
#pragma unroll
      for (int r = 0; r < 4; ++r) {
        float v = z[rg][0][r];
#pragma unroll
        for (int c = 1; c < 8; ++c) v = fmaxf(v, z[rg][c][r]);
        pm[rg][r] = v;
      }
#pragma unroll
    for (int m = 1; m < 16; m <<= 1)
#pragma unroll
      for (int rg = 0; rg < 2; ++rg)
#pragma unroll
        for (int r = 0; r < 4; ++r) pm[rg][r] = fmaxf(pm[rg][r], __shfl_xor(pm[rg][r], m));
    if (lr == 0)
#pragma unroll
      for (int rg = 0; rg < 2; ++rg)
#pragma unroll
        for (int r = 0; r < 4; ++r) red[w][rg * 16 + lg * 4 + r] = pm[rg][r];
    __syncthreads();
#pragma unroll
    for (int rg = 0; rg < 2; ++rg)
#pragma unroll
      for (int r = 0; r < 4; ++r) {
        const int lrow = rg * 16 + lg * 4 + r;
        m1[rg][r] = fmaxf(fmaxf(red[0][lrow], red[1][lrow]), fmaxf(red[2][lrow], red[3][lrow]));
      }
  }
  // ---- softmax 1: denom; overwrite z with exp(z-m1) ----
  float l1i[2][4];
  {
    float ps[2][4] = {};
#pragma unroll
    for (int rg = 0; rg < 2; ++rg)
#pragma unroll
      for (int c = 0; c < 8; ++c)
#pragma unroll
        for (int r = 0; r < 4; ++r) {
          float e = __expf(z[rg][c][r] - m1[rg][r]);
          z[rg][c][r] = e;
          ps[rg][r] += e;
        }
#pragma unroll
    for (int m = 1; m < 16; m <<= 1)
#pragma unroll
      for (int rg = 0; rg < 2; ++rg)
#pragma unroll
        for (int r = 0; r < 4; ++r) ps[rg][r] += __shfl_xor(ps[rg][r], m);
    if (lr == 0)
#pragma unroll
      for (int rg = 0; rg < 2; ++rg)
#pragma unroll
        for (int r = 0; r < 4; ++r) red2[w][rg * 16 + lg * 4 + r] = ps[rg][r];
    __syncthreads();
#pragma unroll
    for (int rg = 0; rg < 2; ++rg)
#pragma unroll
      for (int r = 0; r < 4; ++r) {
        const int lrow = rg * 16 + lg * 4 + r;
        l1i[rg][r] = 1.0f / (red2[0][lrow] + red2[1][lrow] + red2[2][lrow] + red2[3][lrow]);
      }
  }
  // ---- y = w_mn + ExtrAtt (overwrite z) ----
#pragma unroll
  for (int rg = 0; rg < 2; ++rg)
#pragma unroll
    for (int c = 0; c < 8; ++c)
#pragma unroll
      for (int r = 0; r < 4; ++r) {
        const int row = q0 + rg * 16 + lg * 4 + r;
        const int col = w * 128 + c * 16 + lr;
        z[rg][c][r] = z[rg][c][r] * l1i[rg][r] + Ep[(size_t)row * 512 + col];
      }
  // ---- softmax 2: max ----
  float m2[2][4];
  {
    float pm[2][4];
#pragma unroll
    for (int rg = 0; rg < 2; ++rg)
#pragma unroll
      for (int r = 0; r < 4; ++r) {
        float v = z[rg][0][r];
#pragma unroll
        for (int c = 1; c < 8; ++c) v = fmaxf(v, z[rg][c][r]);
        pm[rg][r] = v;
      }
#pragma unroll
    for (int m = 1; m < 16; m <<= 1)
#pragma unroll
      for (int rg = 0; rg < 2; ++rg)
#pragma unroll
        for (int r = 0; r < 4; ++r) pm[rg][r] = fmaxf(pm[rg][r], __shfl_xor(pm[rg][r], m));
    if (lr == 0)
#pragma unroll
      for (int rg = 0; rg < 2; ++rg)
#pragma unroll
        for (int r = 0; r < 4; ++r) red[w][rg * 16 + lg * 4 + r] = pm[rg][r];
    __syncthreads();
#pragma unroll
    for (int rg = 0; rg < 2; ++rg)
#pragma unroll
      for (int r = 0; r < 4; ++r) {
        const int lrow = rg * 16 + lg * 4 + r;
        m2[rg][r] = fmaxf(fmaxf(red[0][lrow], red[1][lrow]), fmaxf(red[2][lrow], red[3][lrow]));
      }
  }
  // ---- softmax 2: denom; overwrite z with exp(y-m2) ----
  float l2i[2][4];
  {
    float ps[2][4] = {};
#pragma unroll
    for (int rg = 0; rg < 2; ++rg)
#pragma unroll
      for (int c = 0; c < 8; ++c)
#pragma unroll
        for (int r = 0; r < 4; ++r) {
          float e = __expf(z[rg][c][r] - m2[rg][r]);
          z[rg][c][r] = e;
          ps[rg][r] += e;
        }
#pragma unroll
    for (int m = 1; m < 16; m <<= 1)
#pragma unroll
      for (int rg = 0; rg < 2; ++rg)
#pragma unroll
        for (int r = 0; r < 4; ++r) ps[rg][r] += __shfl_xor(ps[rg][r], m);
    if (lr == 0)
#pragma unroll
      for (int rg = 0; rg < 2; ++rg)
#pragma unroll
        for (int r = 0; r < 4; ++r) red2[w][rg * 16 + lg * 4 + r] = ps[rg][r];
    __syncthreads();
#pragma unroll
    for (int rg = 0; rg < 2; ++rg)
#pragma unroll
      for (int r = 0; r < 4; ++r) {
        const int lrow = rg * 16 + lg * 4 + r;
        l2i[rg][r] = 1.0f / (red2[0][lrow] + red2[1][lrow] + red2[2][lrow] + red2[3][lrow]);
      }
  }
  // ---- P (normalized, bf16) -> per-wave LDS tile ----
  unsigned short(*Pw)[136] = (unsigned short(*)[136])wsh[w];
#pragma unroll
  for (int rg = 0; rg < 2; ++rg)
#pragma unroll
    for (int c = 0; c < 8; ++c)
#pragma unroll
      for (int r = 0; r < 4; ++r)
        Pw[rg * 16 + lg * 4 + r][c * 16 + lr] = f2bf(z[rg][c][r] * l2i[rg][r]);
  __syncthreads();
  // ---- PV: wave's partial over its 128 keys ----
  f32x4 o[2][4] = {};
#pragma unroll
  for (int kc = 0; kc < 4; ++kc) {
    short8 pa0 = *(const short8*)&Pw[lr][kc * 32 + lg * 8];
    short8 pa1 = *(const short8*)&Pw[16 + lr][kc * 32 + lg * 8];
#pragma unroll
    for (int c2 = 0; c2 < 4; ++c2) {
      short8 vf = *(const short8*)&Vt[(size_t)(c2 * 16 + lr) * 512 + w * 128 + kc * 32 + lg * 8];
      o[0][c2] = __builtin_amdgcn_mfma_f32_16x16x32_bf16(pa0, vf, o[0][c2], 0, 0, 0);
      o[1][c2] = __builtin_amdgcn_mfma_f32_16x16x32_bf16(pa1, vf, o[1][c2], 0, 0, 0);
    }
  }
  // partial out -> own region (aliases P tile; own-wave sequential)
  float* ow = (float*)wsh[w];
#pragma unroll
  for (int rg = 0; rg < 2; ++rg)
#pragma unroll
    for (int c2 = 0; c2 < 4; ++c2)
#pragma unroll
      for (int r = 0; r < 4; ++r)
        ow[(rg * 16 + lg * 4 + r) * 68 + c2 * 16 + lr] = o[rg][c2][r];
  __syncthreads();
  // cross-wave sum + store
#pragma unroll
  for (int i = 0; i < 8; ++i) {
    const int e = t + 256 * i;
    const int lrow = e >> 6, dv = e & 63;
    float s = ((const float*)wsh[0])[lrow * 68 + dv] + ((const float*)wsh[1])[lrow * 68 + dv] +
              ((const float*)wsh[2])[lrow * 68 + dv] + ((const float*)wsh[3])[lrow * 68 + dv];
    hidden[(size_t)(b * 512 + q0 + lrow) * 512 + h * 64 + dv] = f2bf(s);
  }
}

// ---------------------------------------------------------------- kernel 3
// out = hidden[8192x512]bf16 @ WoT + bo  (fp32 out)
__global__ __launch_bounds__(256) void out_gemm(
    const unsigned short* __restrict__ hidden, const unsigned short* __restrict__ WoT,
    const float* __restrict__ bo, float* __restrict__ out) {
  const int m0 = blockIdx.x * 128, n0 = blockIdx.y * 128;
  __shared__ unsigned short Al[2][128][40];
  __shared__ unsigned short Bl[2][128][40];
  const int t = threadIdx.x;
  const int w = t >> 6, l = t & 63;
  const int lr = l & 15, lg = l >> 4;
  const int wr = (w >> 1) * 64, wc = (w & 1) * 64;
  f32x4 acc[4][4] = {};
  for (int kk = 0; kk < 512; kk += 64) {
    __syncthreads();
    {
      const int colk8 = (t & 7) * 8;
      const int kc2 = colk8 >> 5, kin2 = colk8 & 31;
#pragma unroll
      for (int p = 0; p < 4; ++p) {
        int row = p * 32 + (t >> 3);
        short8 v = *(const short8*)&hidden[(size_t)(m0 + row) * 512 + kk + colk8];
        *(short8*)&Al[kc2][row][kin2] = v;
      }
#pragma unroll
      for (int p = 0; p < 4; ++p) {
        int row = p * 32 + (t >> 3);
        short8 v = *(const short8*)&WoT[(size_t)(n0 + row) * 512 + kk + colk8];
        *(short8*)&Bl[kc2][row][kin2] = v;
      }
    }
    __syncthreads();
#pragma unroll
    for (int kc = 0; kc < 2; ++kc) {
      short8 a[4], b[4];
      const int lk = lg * 8;
#pragma unroll
      for (int i = 0; i < 4; ++i) a[i] = *(const short8*)&Al[kc][wr + i * 16 + lr][lk];
#pragma unroll
      for (int i = 0; i < 4; ++i) b[i] = *(const short8*)&Bl[kc][wc + i * 16 + lr][lk];
#pragma unroll
      for (int i = 0; i < 4; ++i)
#pragma unroll
        for (int j = 0; j < 4; ++j)
          acc[i][j] = __builtin_amdgcn_mfma_f32_16x16x32_bf16(a[i], b[j], acc[i][j], 0, 0, 0);
    }
  }
#pragma unroll
  for (int j = 0; j < 4; ++j) {
    const int col = n0 + wc + j * 16 + lr;
    const float bb = bo[col];
#pragma unroll
    for (int i = 0; i < 4; ++i)
#pragma unroll
      for (int r = 0; r < 4; ++r)
        out[(size_t)(m0 + wr + i * 16 + lg * 4 + r) * 512 + col] = acc[i][j][r] + bb;
  }
}

// ---------------------------------------------------------------- launch
extern "C" void kernel_launch(void* const* d_in, const int* in_sizes, int n_in,
                              void* d_out, int out_size, void* d_ws, size_t ws_size,
                              hipStream_t stream) {
  const float* queries = (const float*)d_in[0];
  const float* keys = (const float*)d_in[1];
  const float* values = (const float*)d_in[2];
  const float* box = (const float*)d_in[3];
  const float* ext = (const float*)d_in[4];
  const float* Wq = (const float*)d_in[5];
  const float* bq = (const float*)d_in[6];
  const float* Wk = (const float*)d_in[7];
  const float* bk = (const float*)d_in[8];
  const float* Wv = (const float*)d_in[9];
  const float* bv = (const float*)d_in[10];
  const float* Wo = (const float*)d_in[11];
  const float* bo = (const float*)d_in[12];
  float* out = (float*)d_out;

  char* ws = (char*)d_ws;
  unsigned short* q_ws = (unsigned short*)(ws);
  unsigned short* k_ws = (unsigned short*)(ws + 8u * 1024 * 1024);
  unsigned short* vt_ws = (unsigned short*)(ws + 16u * 1024 * 1024);
  unsigned short* hidden = (unsigned short*)(ws + 24u * 1024 * 1024);
  unsigned short* wt = (unsigned short*)(ws + 32u * 1024 * 1024);  // 4 x 512KB

  wprep<<<dim3(8, 8, 4), 256, 0, stream>>>(Wq, Wk, Wv, Wo, wt);
  qkv_gemm<<<dim3(64, 4, 3), 256, 0, stream>>>(queries, keys, values, wt, bq, bk, bv,
                                               q_ws, k_ws, vt_ws);
  attn_kernel<<<dim3(16, 128), 256, 0, stream>>>(q_ws, k_ws, vt_ws, box, ext, hidden);
  out_gemm<<<dim3(64, 4), 256, 0, stream>>>(hidden, wt + 3u * 512 * 512, bo, out);
}

// Round 2
// 155.893 us; speedup vs baseline: 1.0349x; 1.0349x over previous
//
#include <hip/hip_runtime.h>
#include <hip/hip_bf16.h>

#define NB 16
#define NN 512
#define ND 512
#define NH 8

using short8 = __attribute__((ext_vector_type(8))) short;
using f32x4  = __attribute__((ext_vector_type(4))) float;

static __device__ __forceinline__ unsigned short f2bf(float f) {
  unsigned u = __builtin_bit_cast(unsigned, f);
  unsigned r = 0x7fffu + ((u >> 16) & 1u);
  return (unsigned short)((u + r) >> 16);
}

// ---------------------------------------------------------------- kernel 0
// Transpose 4 weight mats [k][n] fp32 -> [n][k] bf16 (Wq,Wk,Wv,Wo)
__global__ __launch_bounds__(256) void wprep(
    const float* __restrict__ Wq, const float* __restrict__ Wk,
    const float* __restrict__ Wv, const float* __restrict__ Wo,
    unsigned short* __restrict__ T) {
  const float* W;
  switch (blockIdx.z) {
    case 0: W = Wq; break;
    case 1: W = Wk; break;
    case 2: W = Wv; break;
    default: W = Wo; break;
  }
  unsigned short* Wt = T + (size_t)blockIdx.z * 512 * 512;
  __shared__ float tile[64][65];
  const int t = threadIdx.x;
  const int k0 = blockIdx.x * 64, n0 = blockIdx.y * 64;
#pragma unroll
  for (int it = 0; it < 4; ++it) {
    int row = it * 16 + (t >> 4);
    int c4 = (t & 15) * 4;
    float4 v = *(const float4*)&W[(size_t)(k0 + row) * 512 + n0 + c4];
    tile[row][c4] = v.x; tile[row][c4 + 1] = v.y;
    tile[row][c4 + 2] = v.z; tile[row][c4 + 3] = v.w;
  }
  __syncthreads();
#pragma unroll
  for (int it = 0; it < 4; ++it) {
    int nr = it * 16 + (t >> 4);
    int k4 = (t & 15) * 4;
    ushort4 o;
    o.x = f2bf(tile[k4 + 0][nr]); o.y = f2bf(tile[k4 + 1][nr]);
    o.z = f2bf(tile[k4 + 2][nr]); o.w = f2bf(tile[k4 + 3][nr]);
    *(ushort4*)&Wt[(size_t)(n0 + nr) * 512 + k0 + k4] = o;
  }
}

// ---------------------------------------------------------------- kernel 1
// QKV projection: X[8192x512]fp32 @ Wt^T + b -> bf16, scattered to
// q_ws/k_ws [B,H,N,64], vt_ws [B,H,64,N]
__global__ __launch_bounds__(256) void qkv_gemm(
    const float* __restrict__ Xq, const float* __restrict__ Xk,
    const float* __restrict__ Xv, const unsigned short* __restrict__ Wt,
    const float* __restrict__ bq, const float* __restrict__ bk,
    const float* __restrict__ bv, unsigned short* __restrict__ q_ws,
    unsigned short* __restrict__ k_ws, unsigned short* __restrict__ vt_ws) {
  const int zi = blockIdx.z;
  const float* X = (zi == 0) ? Xq : (zi == 1) ? Xk : Xv;
  const unsigned short* Wz = Wt + (size_t)zi * 512 * 512;
  const float* bias = (zi == 0) ? bq : (zi == 1) ? bk : bv;
  const int m0 = blockIdx.x * 128, n0 = blockIdx.y * 128;
  __shared__ unsigned short Al[2][128][40];
  __shared__ unsigned short Bl[2][128][40];
  const int t = threadIdx.x;
  const int w = t >> 6, l = t & 63;
  const int lr = l & 15, lg = l >> 4;
  const int wr = (w >> 1) * 64, wc = (w & 1) * 64;
  f32x4 acc[4][4] = {};
  for (int kk = 0; kk < 512; kk += 64) {
    __syncthreads();
    {
      const int colk = (t & 15) * 4;
      const int kc = colk >> 5, kin = colk & 31;
#pragma unroll
      for (int p = 0; p < 8; ++p) {
        int row = p * 16 + (t >> 4);
        float4 v = *(const float4*)&X[(size_t)(m0 + row) * 512 + kk + colk];
        ushort4 o;
        o.x = f2bf(v.x); o.y = f2bf(v.y); o.z = f2bf(v.z); o.w = f2bf(v.w);
        *(ushort4*)&Al[kc][row][kin] = o;
      }
      const int colk8 = (t & 7) * 8;
      const int kc2 = colk8 >> 5, kin2 = colk8 & 31;
#pragma unroll
      for (int p = 0; p < 4; ++p) {
        int row = p * 32 + (t >> 3);
        short8 v = *(const short8*)&Wz[(size_t)(n0 + row) * 512 + kk + colk8];
        *(short8*)&Bl[kc2][row][kin2] = v;
      }
    }
    __syncthreads();
#pragma unroll
    for (int kc = 0; kc < 2; ++kc) {
      short8 a[4], b[4];
      const int lk = lg * 8;
#pragma unroll
      for (int i = 0; i < 4; ++i) a[i] = *(const short8*)&Al[kc][wr + i * 16 + lr][lk];
#pragma unroll
      for (int i = 0; i < 4; ++i) b[i] = *(const short8*)&Bl[kc][wc + i * 16 + lr][lk];
#pragma unroll
      for (int i = 0; i < 4; ++i)
#pragma unroll
        for (int j = 0; j < 4; ++j)
          acc[i][j] = __builtin_amdgcn_mfma_f32_16x16x32_bf16(a[i], b[j], acc[i][j], 0, 0, 0);
    }
  }
#pragma unroll
  for (int j = 0; j < 4; ++j) {
    const int col = n0 + wc + j * 16 + lr;
    const float bb = bias[col];
    const int hh = col >> 6, dv = col & 63;
#pragma unroll
    for (int i = 0; i < 4; ++i) {
      const int mbase = m0 + wr + i * 16 + lg * 4;
      const int b_ = mbase >> 9, nt = mbase & 511;
      if (zi == 2) {
        ushort4 o;
        o.x = f2bf(acc[i][j][0] + bb); o.y = f2bf(acc[i][j][1] + bb);
        o.z = f2bf(acc[i][j][2] + bb); o.w = f2bf(acc[i][j][3] + bb);
        *(ushort4*)&vt_ws[((size_t)(b_ * NH + hh) * 64 + dv) * 512 + nt] = o;
      } else {
        unsigned short* dst = (zi == 0) ? q_ws : k_ws;
#pragma unroll
        for (int r = 0; r < 4; ++r)
          dst[((size_t)(b_ * NH + hh) * 512 + nt + r) * 64 + dv] = f2bf(acc[i][j][r] + bb);
      }
    }
  }
}

// ---------------------------------------------------------------- kernel 2
// Attention, swapped-operand QK^T: each lane owns one q-row (lr) and 4
// consecutive keys per reg (k = c*16 + lg*4 + r) -> float4 box/Ext loads,
// lane-local row reductions (+2 shfl + tiny LDS cross-wave combine).
__global__ __launch_bounds__(256) void attn_kernel(
    const unsigned short* __restrict__ q_ws, const unsigned short* __restrict__ k_ws,
    const unsigned short* __restrict__ vt_ws, const float* __restrict__ box,
    const float* __restrict__ Ext, unsigned short* __restrict__ hidden) {
  const int t = threadIdx.x;
  const int w = t >> 6, l = t & 63;
  const int lr = l & 15, lg = l >> 4;
  const int bh = blockIdx.y;
  const int q0 = blockIdx.x * 32;
  const int b = bh >> 3, h = bh & 7;

  const unsigned short* Qp = q_ws + (size_t)bh * 512 * 64;
  const unsigned short* Kp = k_ws + (size_t)bh * 512 * 64;
  const unsigned short* Vt = vt_ws + (size_t)bh * 64 * 512;
  const float* boxp = box + ((size_t)bh * 512 + q0) * 512;
  const float* Ep = Ext + ((size_t)bh * 512 + q0) * 512;

  __shared__ float red[4][32];
  __shared__ float red2[4][32];
  // per-wave: P bf16 [32][144] (9216B) aliased with out f32 [32][68] (8704B)
  __shared__ __align__(16) unsigned char wsh[4][9216];

  const int n0w = w * 128;  // this wave's 128-key chunk

  // Q fragments (B operand)
  short8 qf[2][2];
#pragma unroll
  for (int rg = 0; rg < 2; ++rg)
#pragma unroll
    for (int kc = 0; kc < 2; ++kc)
      qf[rg][kc] = *(const short8*)&Qp[(size_t)(q0 + rg * 16 + lr) * 64 + kc * 32 + lg * 8];

  // z^T = (K Q^T): z[rg][c][r] = logits[q = q0+rg*16+lr][k = n0w+c*16+lg*4+r]
  f32x4 z[2][8];
#pragma unroll
  for (int c = 0; c < 8; ++c) {
    const int krow = n0w + c * 16 + lr;
    short8 kf0 = *(const short8*)&Kp[(size_t)krow * 64 + lg * 8];
    short8 kf1 = *(const short8*)&Kp[(size_t)krow * 64 + 32 + lg * 8];
    const int cb = n0w + c * 16 + lg * 4;
    f32x4 bx0 = *(const f32x4*)&boxp[(size_t)(0 * 16 + lr) * 512 + cb];
    f32x4 bx1 = *(const f32x4*)&boxp[(size_t)(1 * 16 + lr) * 512 + cb];
    f32x4 a0 = {0.f, 0.f, 0.f, 0.f}, a1 = {0.f, 0.f, 0.f, 0.f};
    a0 = __builtin_amdgcn_mfma_f32_16x16x32_bf16(kf0, qf[0][0], a0, 0, 0, 0);
    a0 = __builtin_amdgcn_mfma_f32_16x16x32_bf16(kf1, qf[0][1], a0, 0, 0, 0);
    a1 = __builtin_amdgcn_mfma_f32_16x16x32_bf16(kf0, qf[1][0], a1, 0, 0, 0);
    a1 = __builtin_amdgcn_mfma_f32_16x16x32_bf16(kf1, qf[1][1], a1, 0, 0, 0);
#pragma unroll
    for (int r = 0; r < 4; ++r) {
      z[0][c][r] = a0[r] * 0.125f + __logf(fmaxf(bx0[r], 1e-6f));
      z[1][c][r] = a1[r] * 0.125f + __logf(fmaxf(bx1[r], 1e-6f));
    }
  }

  // ---- softmax 1: row max (lane-local + 2 shfl + cross-wave LDS) ----
  float m1f[2];
  {
    float mm[2];
#pragma unroll
    for (int rg = 0; rg < 2; ++rg) {
      f32x4 vm = z[rg][0];
#pragma unroll
      for (int c = 1; c < 8; ++c)
#pragma unroll
        for (int r = 0; r < 4; ++r) vm[r] = fmaxf(vm[r], z[rg][c][r]);
      float m = fmaxf(fmaxf(vm[0], vm[1]), fmaxf(vm[2], vm[3]));
      m = fmaxf(m, __shfl_xor(m, 16));
      m = fmaxf(m, __shfl_xor(m, 32));
      mm[rg] = m;
    }
    if (lg == 0) {
      red[w][lr] = mm[0];
      red[w][16 + lr] = mm[1];
    }
    __syncthreads();
#pragma unroll
    for (int rg = 0; rg < 2; ++rg) {
      const int lrow = rg * 16 + lr;
      m1f[rg] = fmaxf(fmaxf(red[0][lrow], red[1][lrow]), fmaxf(red[2][lrow], red[3][lrow]));
    }
  }
  // ---- softmax 1: denom; z <- exp(z-m1) ----
  float l1i[2];
  {
    float ss[2];
#pragma unroll
    for (int rg = 0; rg < 2; ++rg) {
      f32x4 vs = {0.f, 0.f, 0.f, 0.f};
#pragma unroll
      for (int c = 0; c < 8; ++c)
#pragma unroll
        for (int r = 0; r < 4; ++r) {
          float e = __expf(z[rg][c][r] - m1f[rg]);
          z[rg][c][r] = e;
          vs[r] += e;
        }
      float s = (vs[0] + vs[1]) + (vs[2] + vs[3]);
      s += __shfl_xor(s, 16);
      s += __shfl_xor(s, 32);
      ss[rg] = s;
    }
    if (lg == 0) {
      red2[w][lr] = ss[0];
      red2[w][16 + lr] = ss[1];
    }
    __syncthreads();
#pragma unroll
    for (int rg = 0; rg < 2; ++rg) {
      const int lrow = rg * 16 + lr;
      l1i[rg] = 1.0f / (red2[0][lrow] + red2[1][lrow] + red2[2][lrow] + red2[3][lrow]);
    }
  }
  // ---- y = w_mn + ExtrAtt (float4 Ext loads) ----
#pragma unroll
  for (int rg = 0; rg < 2; ++rg)
#pragma unroll
    for (int c = 0; c < 8; ++c) {
      f32x4 ex = *(const f32x4*)&Ep[(size_t)(rg * 16 + lr) * 512 + n0w + c * 16 + lg * 4];
#pragma unroll
      for (int r = 0; r < 4; ++r) z[rg][c][r] = z[rg][c][r] * l1i[rg] + ex[r];
    }
  // ---- softmax 2: max ----
  float m2f[2];
  {
    float mm[2];
#pragma unroll
    for (int rg = 0; rg < 2; ++rg) {
      f32x4 vm = z[rg][0];
#pragma unroll
      for (int c = 1; c < 8; ++c)
#pragma unroll
        for (int r = 0; r < 4; ++r) vm[r] = fmaxf(vm[r], z[rg][c][r]);
      float m = fmaxf(fmaxf(vm[0], vm[1]), fmaxf(vm[2], vm[3]));
      m = fmaxf(m, __shfl_xor(m, 16));
      m = fmaxf(m, __shfl_xor(m, 32));
      mm[rg] = m;
    }
    if (lg == 0) {
      red[w][lr] = mm[0];
      red[w][16 + lr] = mm[1];
    }
    __syncthreads();
#pragma unroll
    for (int rg = 0; rg < 2; ++rg) {
      const int lrow = rg * 16 + lr;
      m2f[rg] = fmaxf(fmaxf(red[0][lrow], red[1][lrow]), fmaxf(red[2][lrow], red[3][lrow]));
    }
  }
  // ---- softmax 2: denom; z <- exp(y-m2) ----
  float l2i[2];
  {
    float ss[2];
#pragma unroll
    for (int rg = 0; rg < 2; ++rg) {
      f32x4 vs = {0.f, 0.f, 0.f, 0.f};
#pragma unroll
      for (int c = 0; c < 8; ++c)
#pragma unroll
        for (int r = 0; r < 4; ++r) {
          float e = __expf(z[rg][c][r] - m2f[rg]);
          z[rg][c][r] = e;
          vs[r] += e;
        }
      float s = (vs[0] + vs[1]) + (vs[2] + vs[3]);
      s += __shfl_xor(s, 16);
      s += __shfl_xor(s, 32);
      ss[rg] = s;
    }
    if (lg == 0) {
      red2[w][lr] = ss[0];
      red2[w][16 + lr] = ss[1];
    }
    __syncthreads();
#pragma unroll
    for (int rg = 0; rg < 2; ++rg) {
      const int lrow = rg * 16 + lr;
      l2i[rg] = 1.0f / (red2[0][lrow] + red2[1][lrow] + red2[2][lrow] + red2[3][lrow]);
    }
  }
  // ---- P (normalized, bf16) -> per-wave LDS tile [32][144] ----
  unsigned short(*Pw)[144] = (unsigned short(*)[144])wsh[w];
#pragma unroll
  for (int rg = 0; rg < 2; ++rg)
#pragma unroll
    for (int c = 0; c < 8; ++c) {
      ushort4 o;
      o.x = f2bf(z[rg][c][0] * l2i[rg]);
      o.y = f2bf(z[rg][c][1] * l2i[rg]);
      o.z = f2bf(z[rg][c][2] * l2i[rg]);
      o.w = f2bf(z[rg][c][3] * l2i[rg]);
      *(ushort4*)&Pw[rg * 16 + lr][c * 16 + lg * 4] = o;
    }
  __syncthreads();
  // ---- PV: wave's partial over its 128 keys ----
  f32x4 o[2][4] = {};
#pragma unroll
  for (int kc = 0; kc < 4; ++kc) {
    short8 pa0 = *(const short8*)&Pw[lr][kc * 32 + lg * 8];
    short8 pa1 = *(const short8*)&Pw[16 + lr][kc * 32 + lg * 8];
#pragma unroll
    for (int c2 = 0; c2 < 4; ++c2) {
      short8 vf = *(const short8*)&Vt[(size_t)(c2 * 16 + lr) * 512 + n0w + kc * 32 + lg * 8];
      o[0][c2] = __builtin_amdgcn_mfma_f32_16x16x32_bf16(pa0, vf, o[0][c2], 0, 0, 0);
      o[1][c2] = __builtin_amdgcn_mfma_f32_16x16x32_bf16(pa1, vf, o[1][c2], 0, 0, 0);
    }
  }
  // partial out -> own region (aliases P tile; own-wave only)
  float* ow = (float*)wsh[w];
#pragma unroll
  for (int rg = 0; rg < 2; ++rg)
#pragma unroll
    for (int c2 = 0; c2 < 4; ++c2)
#pragma unroll
      for (int r = 0; r < 4; ++r)
        ow[(rg * 16 + lg * 4 + r) * 68 + c2 * 16 + lr] = o[rg][c2][r];
  __syncthreads();
  // cross-wave sum + store
#pragma unroll
  for (int i = 0; i < 8; ++i) {
    const int e = t + 256 * i;
    const int lrow = e >> 6, dv = e & 63;
    float s = ((const float*)wsh[0])[lrow * 68 + dv] + ((const float*)wsh[1])[lrow * 68 + dv] +
              ((const float*)wsh[2])[lrow * 68 + dv] + ((const float*)wsh[3])[lrow * 68 + dv];
    hidden[(size_t)(b * 512 + q0 + lrow) * 512 + h * 64 + dv] = f2bf(s);
  }
}

// ---------------------------------------------------------------- kernel 3
// out = hidden[8192x512]bf16 @ WoT + bo  (fp32 out)
__global__ __launch_bounds__(256) void out_gemm(
    const unsigned short* __restrict__ hidden, const unsigned short* __restrict__ WoT,
    const float* __restrict__ bo, float* __restrict__ out) {
  const int m0 = blockIdx.x * 128, n0 = blockIdx.y * 128;
  __shared__ unsigned short Al[2][128][40];
  __shared__ unsigned short Bl[2][128][40];
  const int t = threadIdx.x;
  const int w = t >> 6, l = t & 63;
  const int lr = l & 15, lg = l >> 4;
  const int wr = (w >> 1) * 64, wc = (w & 1) * 64;
  f32x4 acc[4][4] = {};
  for (int kk = 0; kk < 512; kk += 64) {
    __syncthreads();
    {
      const int colk8 = (t & 7) * 8;
      const int kc2 = colk8 >> 5, kin2 = colk8 & 31;
#pragma unroll
      for (int p = 0; p < 4; ++p) {
        int row = p * 32 + (t >> 3);
        short8 v = *(const short8*)&hidden[(size_t)(m0 + row) * 512 + kk + colk8];
        *(short8*)&Al[kc2][row][kin2] = v;
      }
#pragma unroll
      for (int p = 0; p < 4; ++p) {
        int row = p * 32 + (t >> 3);
        short8 v = *(const short8*)&WoT[(size_t)(n0 + row) * 512 + kk + colk8];
        *(short8*)&Bl[kc2][row][kin2] = v;
      }
    }
    __syncthreads();
#pragma unroll
    for (int kc = 0; kc < 2; ++kc) {
      short8 a[4], b[4];
      const int lk = lg * 8;
#pragma unroll
      for (int i = 0; i < 4; ++i) a[i] = *(const short8*)&Al[kc][wr + i * 16 + lr][lk];
#pragma unroll
      for (int i = 0; i < 4; ++i) b[i] = *(const short8*)&Bl[kc][wc + i * 16 + lr][lk];
#pragma unroll
      for (int i = 0; i < 4; ++i)
#pragma unroll
        for (int j = 0; j < 4; ++j)
          acc[i][j] = __builtin_amdgcn_mfma_f32_16x16x32_bf16(a[i], b[j], acc[i][j], 0, 0, 0);
    }
  }
#pragma unroll
  for (int j = 0; j < 4; ++j) {
    const int col = n0 + wc + j * 16 + lr;
    const float bb = bo[col];
#pragma unroll
    for (int i = 0; i < 4; ++i)
#pragma unroll
      for (int r = 0; r < 4; ++r)
        out[(size_t)(m0 + wr + i * 16 + lg * 4 + r) * 512 + col] = acc[i][j][r] + bb;
  }
}

// ---------------------------------------------------------------- launch
extern "C" void kernel_launch(void* const* d_in, const int* in_sizes, int n_in,
                              void* d_out, int out_size, void* d_ws, size_t ws_size,
                              hipStream_t stream) {
  const float* queries = (const float*)d_in[0];
  const float* keys = (const float*)d_in[1];
  const float* values = (const float*)d_in[2];
  const float* box = (const float*)d_in[3];
  const float* ext = (const float*)d_in[4];
  const float* Wq = (const float*)d_in[5];
  const float* bq = (const float*)d_in[6];
  const float* Wk = (const float*)d_in[7];
  const float* bk = (const float*)d_in[8];
  const float* Wv = (const float*)d_in[9];
  const float* bv = (const float*)d_in[10];
  const float* Wo = (const float*)d_in[11];
  const float* bo = (const float*)d_in[12];
  float* out = (float*)d_out;

  char* ws = (char*)d_ws;
  unsigned short* q_ws = (unsigned short*)(ws);
  unsigned short* k_ws = (unsigned short*)(ws + 8u * 1024 * 1024);
  unsigned short* vt_ws = (unsigned short*)(ws + 16u * 1024 * 1024);
  unsigned short* hidden = (unsigned short*)(ws + 24u * 1024 * 1024);
  unsigned short* wt = (unsigned short*)(ws + 32u * 1024 * 1024);  // 4 x 512KB

  wprep<<<dim3(8, 8, 4), 256, 0, stream>>>(Wq, Wk, Wv, Wo, wt);
  qkv_gemm<<<dim3(64, 4, 3), 256, 0, stream>>>(queries, keys, values, wt, bq, bk, bv,
                                               q_ws, k_ws, vt_ws);
  attn_kernel<<<dim3(16, 128), 256, 0, stream>>>(q_ws, k_ws, vt_ws, box, ext, hidden);
  out_gemm<<<dim3(64, 4), 256, 0, stream>>>(hidden, wt + 3u * 512 * 512, bo, out);
}

// Round 3
// 150.523 us; speedup vs baseline: 1.0718x; 1.0357x over previous
//
#include <hip/hip_runtime.h>
#include <hip/hip_bf16.h>

#define NB 16
#define NN 512
#define ND 512
#define NH 8

using short8 = __attribute__((ext_vector_type(8))) short;
using f32x4  = __attribute__((ext_vector_type(4))) float;

static __device__ __forceinline__ unsigned short f2bf(float f) {
  unsigned u = __builtin_bit_cast(unsigned, f);
  unsigned r = 0x7fffu + ((u >> 16) & 1u);
  return (unsigned short)((u + r) >> 16);
}

// ---------------------------------------------------------------- kernel 0
// Transpose 4 weight mats [k][n] fp32 -> [n][k] bf16 (Wq,Wk,Wv,Wo)
__global__ __launch_bounds__(256) void wprep(
    const float* __restrict__ Wq, const float* __restrict__ Wk,
    const float* __restrict__ Wv, const float* __restrict__ Wo,
    unsigned short* __restrict__ T) {
  const float* W;
  switch (blockIdx.z) {
    case 0: W = Wq; break;
    case 1: W = Wk; break;
    case 2: W = Wv; break;
    default: W = Wo; break;
  }
  unsigned short* Wt = T + (size_t)blockIdx.z * 512 * 512;
  __shared__ float tile[64][65];
  const int t = threadIdx.x;
  const int k0 = blockIdx.x * 64, n0 = blockIdx.y * 64;
#pragma unroll
  for (int it = 0; it < 4; ++it) {
    int row = it * 16 + (t >> 4);
    int c4 = (t & 15) * 4;
    float4 v = *(const float4*)&W[(size_t)(k0 + row) * 512 + n0 + c4];
    tile[row][c4] = v.x; tile[row][c4 + 1] = v.y;
    tile[row][c4 + 2] = v.z; tile[row][c4 + 3] = v.w;
  }
  __syncthreads();
#pragma unroll
  for (int it = 0; it < 4; ++it) {
    int nr = it * 16 + (t >> 4);
    int k4 = (t & 15) * 4;
    ushort4 o;
    o.x = f2bf(tile[k4 + 0][nr]); o.y = f2bf(tile[k4 + 1][nr]);
    o.z = f2bf(tile[k4 + 2][nr]); o.w = f2bf(tile[k4 + 3][nr]);
    *(ushort4*)&Wt[(size_t)(n0 + nr) * 512 + k0 + k4] = o;
  }
}

// ---------------------------------------------------------------- kernel 1
// QKV projection: X[8192x512]fp32 @ Wt^T + b -> bf16, scattered to
// q_ws/k_ws [B,H,N,64], vt_ws [B,H,64,N]
__global__ __launch_bounds__(256) void qkv_gemm(
    const float* __restrict__ Xq, const float* __restrict__ Xk,
    const float* __restrict__ Xv, const unsigned short* __restrict__ Wt,
    const float* __restrict__ bq, const float* __restrict__ bk,
    const float* __restrict__ bv, unsigned short* __restrict__ q_ws,
    unsigned short* __restrict__ k_ws, unsigned short* __restrict__ vt_ws) {
  const int zi = blockIdx.z;
  const float* X = (zi == 0) ? Xq : (zi == 1) ? Xk : Xv;
  const unsigned short* Wz = Wt + (size_t)zi * 512 * 512;
  const float* bias = (zi == 0) ? bq : (zi == 1) ? bk : bv;
  const int m0 = blockIdx.x * 128, n0 = blockIdx.y * 128;
  __shared__ unsigned short Al[2][128][40];
  __shared__ unsigned short Bl[2][128][40];
  const int t = threadIdx.x;
  const int w = t >> 6, l = t & 63;
  const int lr = l & 15, lg = l >> 4;
  const int wr = (w >> 1) * 64, wc = (w & 1) * 64;
  f32x4 acc[4][4] = {};
  for (int kk = 0; kk < 512; kk += 64) {
    __syncthreads();
    {
      const int colk = (t & 15) * 4;
      const int kc = colk >> 5, kin = colk & 31;
#pragma unroll
      for (int p = 0; p < 8; ++p) {
        int row = p * 16 + (t >> 4);
        float4 v = *(const float4*)&X[(size_t)(m0 + row) * 512 + kk + colk];
        ushort4 o;
        o.x = f2bf(v.x); o.y = f2bf(v.y); o.z = f2bf(v.z); o.w = f2bf(v.w);
        *(ushort4*)&Al[kc][row][kin] = o;
      }
      const int colk8 = (t & 7) * 8;
      const int kc2 = colk8 >> 5, kin2 = colk8 & 31;
#pragma unroll
      for (int p = 0; p < 4; ++p) {
        int row = p * 32 + (t >> 3);
        short8 v = *(const short8*)&Wz[(size_t)(n0 + row) * 512 + kk + colk8];
        *(short8*)&Bl[kc2][row][kin2] = v;
      }
    }
    __syncthreads();
#pragma unroll
    for (int kc = 0; kc < 2; ++kc) {
      short8 a[4], b[4];
      const int lk = lg * 8;
#pragma unroll
      for (int i = 0; i < 4; ++i) a[i] = *(const short8*)&Al[kc][wr + i * 16 + lr][lk];
#pragma unroll
      for (int i = 0; i < 4; ++i) b[i] = *(const short8*)&Bl[kc][wc + i * 16 + lr][lk];
#pragma unroll
      for (int i = 0; i < 4; ++i)
#pragma unroll
        for (int j = 0; j < 4; ++j)
          acc[i][j] = __builtin_amdgcn_mfma_f32_16x16x32_bf16(a[i], b[j], acc[i][j], 0, 0, 0);
    }
  }
#pragma unroll
  for (int j = 0; j < 4; ++j) {
    const int col = n0 + wc + j * 16 + lr;
    const float bb = bias[col];
    const int hh = col >> 6, dv = col & 63;
#pragma unroll
    for (int i = 0; i < 4; ++i) {
      const int mbase = m0 + wr + i * 16 + lg * 4;
      const int b_ = mbase >> 9, nt = mbase & 511;
      if (zi == 2) {
        ushort4 o;
        o.x = f2bf(acc[i][j][0] + bb); o.y = f2bf(acc[i][j][1] + bb);
        o.z = f2bf(acc[i][j][2] + bb); o.w = f2bf(acc[i][j][3] + bb);
        *(ushort4*)&vt_ws[((size_t)(b_ * NH + hh) * 64 + dv) * 512 + nt] = o;
      } else {
        unsigned short* dst = (zi == 0) ? q_ws : k_ws;
#pragma unroll
        for (int r = 0; r < 4; ++r)
          dst[((size_t)(b_ * NH + hh) * 512 + nt + r) * 64 + dv] = f2bf(acc[i][j][r] + bb);
      }
    }
  }
}

// ---------------------------------------------------------------- kernel 2
// Attention, swapped-operand QK^T. v3: no-max softmax (bounded logits),
// full register prefetch of box (before pass1) and Ext (before sum1 barrier)
// to maximize loads-in-flight; launch_bounds(256,3) to permit ~170 VGPR.
__global__ __launch_bounds__(256, 3) void attn_kernel(
    const unsigned short* __restrict__ q_ws, const unsigned short* __restrict__ k_ws,
    const unsigned short* __restrict__ vt_ws, const float* __restrict__ box,
    const float* __restrict__ Ext, unsigned short* __restrict__ hidden) {
  const int t = threadIdx.x;
  const int w = t >> 6, l = t & 63;
  const int lr = l & 15, lg = l >> 4;
  const int bh = blockIdx.y;
  const int q0 = blockIdx.x * 32;
  const int b = bh >> 3, h = bh & 7;

  const unsigned short* Qp = q_ws + (size_t)bh * 512 * 64;
  const unsigned short* Kp = k_ws + (size_t)bh * 512 * 64;
  const unsigned short* Vt = vt_ws + (size_t)bh * 64 * 512;
  const float* boxp = box + ((size_t)bh * 512 + q0) * 512;
  const float* Ep = Ext + ((size_t)bh * 512 + q0) * 512;

  __shared__ float red[4][32];
  __shared__ float red2[4][32];
  // per-wave: P bf16 [32][144] (9216B) aliased with out f32 [32][68] (8704B)
  __shared__ __align__(16) unsigned char wsh[4][9216];

  const int n0w = w * 128;  // this wave's 128-key chunk

  // ---- prefetch box: 16 independent float4 loads, all in flight ----
  f32x4 bx[2][8];
#pragma unroll
  for (int c = 0; c < 8; ++c) {
    const int cb = n0w + c * 16 + lg * 4;
    bx[0][c] = *(const f32x4*)&boxp[(size_t)lr * 512 + cb];
    bx[1][c] = *(const f32x4*)&boxp[(size_t)(16 + lr) * 512 + cb];
  }

  // Q fragments (B operand)
  short8 qf[2][2];
#pragma unroll
  for (int rg = 0; rg < 2; ++rg)
#pragma unroll
    for (int kc = 0; kc < 2; ++kc)
      qf[rg][kc] = *(const short8*)&Qp[(size_t)(q0 + rg * 16 + lr) * 64 + kc * 32 + lg * 8];

  // ---- fused pass1: z^T = K Q^T; e1 = exp(z*scale + log(clip(box))); sum ----
  // z[rg][c][r] holds e1 for [q = q0+rg*16+lr][k = n0w+c*16+lg*4+r]
  f32x4 z[2][8];
  float s1a = 0.f, s1b = 0.f;
#pragma unroll
  for (int c = 0; c < 8; ++c) {
    const int krow = n0w + c * 16 + lr;
    short8 kf0 = *(const short8*)&Kp[(size_t)krow * 64 + lg * 8];
    short8 kf1 = *(const short8*)&Kp[(size_t)krow * 64 + 32 + lg * 8];
    f32x4 a0 = {0.f, 0.f, 0.f, 0.f}, a1 = {0.f, 0.f, 0.f, 0.f};
    a0 = __builtin_amdgcn_mfma_f32_16x16x32_bf16(kf0, qf[0][0], a0, 0, 0, 0);
    a0 = __builtin_amdgcn_mfma_f32_16x16x32_bf16(kf1, qf[0][1], a0, 0, 0, 0);
    a1 = __builtin_amdgcn_mfma_f32_16x16x32_bf16(kf0, qf[1][0], a1, 0, 0, 0);
    a1 = __builtin_amdgcn_mfma_f32_16x16x32_bf16(kf1, qf[1][1], a1, 0, 0, 0);
#pragma unroll
    for (int r = 0; r < 4; ++r) {
      float e0 = __expf(a0[r] * 0.125f + __logf(fmaxf(bx[0][c][r], 1e-6f)));
      float e1 = __expf(a1[r] * 0.125f + __logf(fmaxf(bx[1][c][r], 1e-6f)));
      z[0][c][r] = e0; s1a += e0;
      z[1][c][r] = e1; s1b += e1;
    }
  }
  s1a += __shfl_xor(s1a, 16); s1a += __shfl_xor(s1a, 32);
  s1b += __shfl_xor(s1b, 16); s1b += __shfl_xor(s1b, 32);
  if (lg == 0) {
    red[w][lr] = s1a;
    red[w][16 + lr] = s1b;
  }
  // ---- prefetch Ext: 16 independent float4 loads, hidden under barrier ----
  f32x4 ex[2][8];
#pragma unroll
  for (int c = 0; c < 8; ++c) {
    const int cb = n0w + c * 16 + lg * 4;
    ex[0][c] = *(const f32x4*)&Ep[(size_t)lr * 512 + cb];
    ex[1][c] = *(const f32x4*)&Ep[(size_t)(16 + lr) * 512 + cb];
  }
  __syncthreads();
  float l1i[2];
#pragma unroll
  for (int rg = 0; rg < 2; ++rg) {
    const int lrow = rg * 16 + lr;
    l1i[rg] = 1.0f / (red[0][lrow] + red[1][lrow] + red[2][lrow] + red[3][lrow]);
  }
  // ---- pass2: y = w_mn + Ext; e2 = exp(y); sum ----
  float s2a = 0.f, s2b = 0.f;
#pragma unroll
  for (int c = 0; c < 8; ++c)
#pragma unroll
    for (int r = 0; r < 4; ++r) {
      float e0 = __expf(z[0][c][r] * l1i[0] + ex[0][c][r]);
      float e1 = __expf(z[1][c][r] * l1i[1] + ex[1][c][r]);
      z[0][c][r] = e0; s2a += e0;
      z[1][c][r] = e1; s2b += e1;
    }
  s2a += __shfl_xor(s2a, 16); s2a += __shfl_xor(s2a, 32);
  s2b += __shfl_xor(s2b, 16); s2b += __shfl_xor(s2b, 32);
  if (lg == 0) {
    red2[w][lr] = s2a;
    red2[w][16 + lr] = s2b;
  }
  __syncthreads();
  float l2i[2];
#pragma unroll
  for (int rg = 0; rg < 2; ++rg) {
    const int lrow = rg * 16 + lr;
    l2i[rg] = 1.0f / (red2[0][lrow] + red2[1][lrow] + red2[2][lrow] + red2[3][lrow]);
  }
  // ---- P (normalized, bf16) -> per-wave LDS tile [32][144] ----
  unsigned short(*Pw)[144] = (unsigned short(*)[144])wsh[w];
#pragma unroll
  for (int rg = 0; rg < 2; ++rg)
#pragma unroll
    for (int c = 0; c < 8; ++c) {
      ushort4 o;
      o.x = f2bf(z[rg][c][0] * l2i[rg]);
      o.y = f2bf(z[rg][c][1] * l2i[rg]);
      o.z = f2bf(z[rg][c][2] * l2i[rg]);
      o.w = f2bf(z[rg][c][3] * l2i[rg]);
      *(ushort4*)&Pw[rg * 16 + lr][c * 16 + lg * 4] = o;
    }
  // own-wave LDS region: wave-lockstep ds ordering makes a barrier unnecessary
  // ---- PV: wave's partial over its 128 keys ----
  f32x4 o[2][4] = {};
#pragma unroll
  for (int kc = 0; kc < 4; ++kc) {
    short8 pa0 = *(const short8*)&Pw[lr][kc * 32 + lg * 8];
    short8 pa1 = *(const short8*)&Pw[16 + lr][kc * 32 + lg * 8];
#pragma unroll
    for (int c2 = 0; c2 < 4; ++c2) {
      short8 vf = *(const short8*)&Vt[(size_t)(c2 * 16 + lr) * 512 + n0w + kc * 32 + lg * 8];
      o[0][c2] = __builtin_amdgcn_mfma_f32_16x16x32_bf16(pa0, vf, o[0][c2], 0, 0, 0);
      o[1][c2] = __builtin_amdgcn_mfma_f32_16x16x32_bf16(pa1, vf, o[1][c2], 0, 0, 0);
    }
  }
  // partial out -> own region (aliases P tile; own-wave only)
  float* ow = (float*)wsh[w];
#pragma unroll
  for (int rg = 0; rg < 2; ++rg)
#pragma unroll
    for (int c2 = 0; c2 < 4; ++c2)
#pragma unroll
      for (int r = 0; r < 4; ++r)
        ow[(rg * 16 + lg * 4 + r) * 68 + c2 * 16 + lr] = o[rg][c2][r];
  __syncthreads();
  // cross-wave sum + store
#pragma unroll
  for (int i = 0; i < 8; ++i) {
    const int e = t + 256 * i;
    const int lrow = e >> 6, dv = e & 63;
    float s = ((const float*)wsh[0])[lrow * 68 + dv] + ((const float*)wsh[1])[lrow * 68 + dv] +
              ((const float*)wsh[2])[lrow * 68 + dv] + ((const float*)wsh[3])[lrow * 68 + dv];
    hidden[(size_t)(b * 512 + q0 + lrow) * 512 + h * 64 + dv] = f2bf(s);
  }
}

// ---------------------------------------------------------------- kernel 3
// out = hidden[8192x512]bf16 @ WoT + bo  (fp32 out)
__global__ __launch_bounds__(256) void out_gemm(
    const unsigned short* __restrict__ hidden, const unsigned short* __restrict__ WoT,
    const float* __restrict__ bo, float* __restrict__ out) {
  const int m0 = blockIdx.x * 128, n0 = blockIdx.y * 128;
  __shared__ unsigned short Al[2][128][40];
  __shared__ unsigned short Bl[2][128][40];
  const int t = threadIdx.x;
  const int w = t >> 6, l = t & 63;
  const int lr = l & 15, lg = l >> 4;
  const int wr = (w >> 1) * 64, wc = (w & 1) * 64;
  f32x4 acc[4][4] = {};
  for (int kk = 0; kk < 512; kk += 64) {
    __syncthreads();
    {
      const int colk8 = (t & 7) * 8;
      const int kc2 = colk8 >> 5, kin2 = colk8 & 31;
#pragma unroll
      for (int p = 0; p < 4; ++p) {
        int row = p * 32 + (t >> 3);
        short8 v = *(const short8*)&hidden[(size_t)(m0 + row) * 512 + kk + colk8];
        *(short8*)&Al[kc2][row][kin2] = v;
      }
#pragma unroll
      for (int p = 0; p < 4; ++p) {
        int row = p * 32 + (t >> 3);
        short8 v = *(const short8*)&WoT[(size_t)(n0 + row) * 512 + kk + colk8];
        *(short8*)&Bl[kc2][row][kin2] = v;
      }
    }
    __syncthreads();
#pragma unroll
    for (int kc = 0; kc < 2; ++kc) {
      short8 a[4], b[4];
      const int lk = lg * 8;
#pragma unroll
      for (int i = 0; i < 4; ++i) a[i] = *(const short8*)&Al[kc][wr + i * 16 + lr][lk];
#pragma unroll
      for (int i = 0; i < 4; ++i) b[i] = *(const short8*)&Bl[kc][wc + i * 16 + lr][lk];
#pragma unroll
      for (int i = 0; i < 4; ++i)
#pragma unroll
        for (int j = 0; j < 4; ++j)
          acc[i][j] = __builtin_amdgcn_mfma_f32_16x16x32_bf16(a[i], b[j], acc[i][j], 0, 0, 0);
    }
  }
#pragma unroll
  for (int j = 0; j < 4; ++j) {
    const int col = n0 + wc + j * 16 + lr;
    const float bb = bo[col];
#pragma unroll
    for (int i = 0; i < 4; ++i)
#pragma unroll
      for (int r = 0; r < 4; ++r)
        out[(size_t)(m0 + wr + i * 16 + lg * 4 + r) * 512 + col] = acc[i][j][r] + bb;
  }
}

// ---------------------------------------------------------------- launch
extern "C" void kernel_launch(void* const* d_in, const int* in_sizes, int n_in,
                              void* d_out, int out_size, void* d_ws, size_t ws_size,
                              hipStream_t stream) {
  const float* queries = (const float*)d_in[0];
  const float* keys = (const float*)d_in[1];
  const float* values = (const float*)d_in[2];
  const float* box = (const float*)d_in[3];
  const float* ext = (const float*)d_in[4];
  const float* Wq = (const float*)d_in[5];
  const float* bq = (const float*)d_in[6];
  const float* Wk = (const float*)d_in[7];
  const float* bk = (const float*)d_in[8];
  const float* Wv = (const float*)d_in[9];
  const float* bv = (const float*)d_in[10];
  const float* Wo = (const float*)d_in[11];
  const float* bo = (const float*)d_in[12];
  float* out = (float*)d_out;

  char* ws = (char*)d_ws;
  unsigned short* q_ws = (unsigned short*)(ws);
  unsigned short* k_ws = (unsigned short*)(ws + 8u * 1024 * 1024);
  unsigned short* vt_ws = (unsigned short*)(ws + 16u * 1024 * 1024);
  unsigned short* hidden = (unsigned short*)(ws + 24u * 1024 * 1024);
  unsigned short* wt = (unsigned short*)(ws + 32u * 1024 * 1024);  // 4 x 512KB

  wprep<<<dim3(8, 8, 4), 256, 0, stream>>>(Wq, Wk, Wv, Wo, wt);
  qkv_gemm<<<dim3(64, 4, 3), 256, 0, stream>>>(queries, keys, values, wt, bq, bk, bv,
                                               q_ws, k_ws, vt_ws);
  attn_kernel<<<dim3(16, 128), 256, 0, stream>>>(q_ws, k_ws, vt_ws, box, ext, hidden);
  out_gemm<<<dim3(64, 4), 256, 0, stream>>>(hidden, wt + 3u * 512 * 512, bo, out);
}

// Round 4
// 146.747 us; speedup vs baseline: 1.0994x; 1.0257x over previous
//
#include <hip/hip_runtime.h>
#include <hip/hip_bf16.h>

#define NB 16
#define NN 512
#define ND 512
#define NH 8

using short8 = __attribute__((ext_vector_type(8))) short;
using f32x4  = __attribute__((ext_vector_type(4))) float;

static __device__ __forceinline__ unsigned short f2bf(float f) {
  unsigned u = __builtin_bit_cast(unsigned, f);
  unsigned r = 0x7fffu + ((u >> 16) & 1u);
  return (unsigned short)((u + r) >> 16);
}

// ---------------------------------------------------------------- kernel 0
// Transpose 4 weight mats [k][n] fp32 -> [n][k] bf16 (Wq,Wk,Wv,Wo)
__global__ __launch_bounds__(256) void wprep(
    const float* __restrict__ Wq, const float* __restrict__ Wk,
    const float* __restrict__ Wv, const float* __restrict__ Wo,
    unsigned short* __restrict__ T) {
  const float* W;
  switch (blockIdx.z) {
    case 0: W = Wq; break;
    case 1: W = Wk; break;
    case 2: W = Wv; break;
    default: W = Wo; break;
  }
  unsigned short* Wt = T + (size_t)blockIdx.z * 512 * 512;
  __shared__ float tile[64][65];
  const int t = threadIdx.x;
  const int k0 = blockIdx.x * 64, n0 = blockIdx.y * 64;
#pragma unroll
  for (int it = 0; it < 4; ++it) {
    int row = it * 16 + (t >> 4);
    int c4 = (t & 15) * 4;
    float4 v = *(const float4*)&W[(size_t)(k0 + row) * 512 + n0 + c4];
    tile[row][c4] = v.x; tile[row][c4 + 1] = v.y;
    tile[row][c4 + 2] = v.z; tile[row][c4 + 3] = v.w;
  }
  __syncthreads();
#pragma unroll
  for (int it = 0; it < 4; ++it) {
    int nr = it * 16 + (t >> 4);
    int k4 = (t & 15) * 4;
    ushort4 o;
    o.x = f2bf(tile[k4 + 0][nr]); o.y = f2bf(tile[k4 + 1][nr]);
    o.z = f2bf(tile[k4 + 2][nr]); o.w = f2bf(tile[k4 + 3][nr]);
    *(ushort4*)&Wt[(size_t)(n0 + nr) * 512 + k0 + k4] = o;
  }
}

// ---------------------------------------------------------------- kernel 1
// QKV projection: X[8192x512]fp32 @ Wt^T + b -> bf16, scattered to
// q_ws/k_ws [B,H,N,64], vt_ws [B,H,64,N]
__global__ __launch_bounds__(256) void qkv_gemm(
    const float* __restrict__ Xq, const float* __restrict__ Xk,
    const float* __restrict__ Xv, const unsigned short* __restrict__ Wt,
    const float* __restrict__ bq, const float* __restrict__ bk,
    const float* __restrict__ bv, unsigned short* __restrict__ q_ws,
    unsigned short* __restrict__ k_ws, unsigned short* __restrict__ vt_ws) {
  const int zi = blockIdx.z;
  const float* X = (zi == 0) ? Xq : (zi == 1) ? Xk : Xv;
  const unsigned short* Wz = Wt + (size_t)zi * 512 * 512;
  const float* bias = (zi == 0) ? bq : (zi == 1) ? bk : bv;
  const int m0 = blockIdx.x * 128, n0 = blockIdx.y * 128;
  __shared__ unsigned short Al[2][128][40];
  __shared__ unsigned short Bl[2][128][40];
  const int t = threadIdx.x;
  const int w = t >> 6, l = t & 63;
  const int lr = l & 15, lg = l >> 4;
  const int wr = (w >> 1) * 64, wc = (w & 1) * 64;
  f32x4 acc[4][4] = {};
  for (int kk = 0; kk < 512; kk += 64) {
    __syncthreads();
    {
      const int colk = (t & 15) * 4;
      const int kc = colk >> 5, kin = colk & 31;
#pragma unroll
      for (int p = 0; p < 8; ++p) {
        int row = p * 16 + (t >> 4);
        float4 v = *(const float4*)&X[(size_t)(m0 + row) * 512 + kk + colk];
        ushort4 o;
        o.x = f2bf(v.x); o.y = f2bf(v.y); o.z = f2bf(v.z); o.w = f2bf(v.w);
        *(ushort4*)&Al[kc][row][kin] = o;
      }
      const int colk8 = (t & 7) * 8;
      const int kc2 = colk8 >> 5, kin2 = colk8 & 31;
#pragma unroll
      for (int p = 0; p < 4; ++p) {
        int row = p * 32 + (t >> 3);
        short8 v = *(const short8*)&Wz[(size_t)(n0 + row) * 512 + kk + colk8];
        *(short8*)&Bl[kc2][row][kin2] = v;
      }
    }
    __syncthreads();
#pragma unroll
    for (int kc = 0; kc < 2; ++kc) {
      short8 a[4], b[4];
      const int lk = lg * 8;
#pragma unroll
      for (int i = 0; i < 4; ++i) a[i] = *(const short8*)&Al[kc][wr + i * 16 + lr][lk];
#pragma unroll
      for (int i = 0; i < 4; ++i) b[i] = *(const short8*)&Bl[kc][wc + i * 16 + lr][lk];
#pragma unroll
      for (int i = 0; i < 4; ++i)
#pragma unroll
        for (int j = 0; j < 4; ++j)
          acc[i][j] = __builtin_amdgcn_mfma_f32_16x16x32_bf16(a[i], b[j], acc[i][j], 0, 0, 0);
    }
  }
#pragma unroll
  for (int j = 0; j < 4; ++j) {
    const int col = n0 + wc + j * 16 + lr;
    const float bb = bias[col];
    const int hh = col >> 6, dv = col & 63;
#pragma unroll
    for (int i = 0; i < 4; ++i) {
      const int mbase = m0 + wr + i * 16 + lg * 4;
      const int b_ = mbase >> 9, nt = mbase & 511;
      if (zi == 2) {
        ushort4 o;
        o.x = f2bf(acc[i][j][0] + bb); o.y = f2bf(acc[i][j][1] + bb);
        o.z = f2bf(acc[i][j][2] + bb); o.w = f2bf(acc[i][j][3] + bb);
        *(ushort4*)&vt_ws[((size_t)(b_ * NH + hh) * 64 + dv) * 512 + nt] = o;
      } else {
        unsigned short* dst = (zi == 0) ? q_ws : k_ws;
#pragma unroll
        for (int r = 0; r < 4; ++r)
          dst[((size_t)(b_ * NH + hh) * 512 + nt + r) * 64 + dv] = f2bf(acc[i][j][r] + bb);
      }
    }
  }
}

// ---------------------------------------------------------------- kernel 2
// Attention, swapped-operand QK^T. v4: sched_barrier(0)-pinned register
// prefetch of box (before pass1) and Ext (before sum1 barrier) so 16 loads
// stay in flight per phase (Little's law: need ~9KB/CU in flight for peak).
__global__ __launch_bounds__(256, 3) void attn_kernel(
    const unsigned short* __restrict__ q_ws, const unsigned short* __restrict__ k_ws,
    const unsigned short* __restrict__ vt_ws, const float* __restrict__ box,
    const float* __restrict__ Ext, unsigned short* __restrict__ hidden) {
  const int t = threadIdx.x;
  const int w = t >> 6, l = t & 63;
  const int lr = l & 15, lg = l >> 4;
  const int bh = blockIdx.y;
  const int q0 = blockIdx.x * 32;
  const int b = bh >> 3, h = bh & 7;

  const unsigned short* Qp = q_ws + (size_t)bh * 512 * 64;
  const unsigned short* Kp = k_ws + (size_t)bh * 512 * 64;
  const unsigned short* Vt = vt_ws + (size_t)bh * 64 * 512;
  const float* boxp = box + ((size_t)bh * 512 + q0) * 512;
  const float* Ep = Ext + ((size_t)bh * 512 + q0) * 512;

  __shared__ float red[4][32];
  __shared__ float red2[4][32];
  // per-wave: P bf16 [32][144] (9216B) aliased with out f32 [32][68] (8704B)
  __shared__ __align__(16) unsigned char wsh[4][9216];

  const int n0w = w * 128;  // this wave's 128-key chunk

  // ---- prefetch box: 16 independent float4 loads, pinned early ----
  f32x4 bx[2][8];
#pragma unroll
  for (int c = 0; c < 8; ++c) {
    const int cb = n0w + c * 16 + lg * 4;
    bx[0][c] = *(const f32x4*)&boxp[(size_t)lr * 512 + cb];
    bx[1][c] = *(const f32x4*)&boxp[(size_t)(16 + lr) * 512 + cb];
  }
  // scheduler fence: loads above may not sink below this point
  __builtin_amdgcn_sched_barrier(0);

  // Q fragments (B operand)
  short8 qf[2][2];
#pragma unroll
  for (int rg = 0; rg < 2; ++rg)
#pragma unroll
    for (int kc = 0; kc < 2; ++kc)
      qf[rg][kc] = *(const short8*)&Qp[(size_t)(q0 + rg * 16 + lr) * 64 + kc * 32 + lg * 8];

  // ---- fused pass1: z^T = K Q^T; e1 = exp(z*scale + log(clip(box))); sum ----
  // z[rg][c][r] holds e1 for [q = q0+rg*16+lr][k = n0w+c*16+lg*4+r]
  f32x4 z[2][8];
  float s1a = 0.f, s1b = 0.f;
#pragma unroll
  for (int c = 0; c < 8; ++c) {
    const int krow = n0w + c * 16 + lr;
    short8 kf0 = *(const short8*)&Kp[(size_t)krow * 64 + lg * 8];
    short8 kf1 = *(const short8*)&Kp[(size_t)krow * 64 + 32 + lg * 8];
    f32x4 a0 = {0.f, 0.f, 0.f, 0.f}, a1 = {0.f, 0.f, 0.f, 0.f};
    a0 = __builtin_amdgcn_mfma_f32_16x16x32_bf16(kf0, qf[0][0], a0, 0, 0, 0);
    a0 = __builtin_amdgcn_mfma_f32_16x16x32_bf16(kf1, qf[0][1], a0, 0, 0, 0);
    a1 = __builtin_amdgcn_mfma_f32_16x16x32_bf16(kf0, qf[1][0], a1, 0, 0, 0);
    a1 = __builtin_amdgcn_mfma_f32_16x16x32_bf16(kf1, qf[1][1], a1, 0, 0, 0);
#pragma unroll
    for (int r = 0; r < 4; ++r) {
      float e0 = __expf(a0[r] * 0.125f + __logf(fmaxf(bx[0][c][r], 1e-6f)));
      float e1 = __expf(a1[r] * 0.125f + __logf(fmaxf(bx[1][c][r], 1e-6f)));
      z[0][c][r] = e0; s1a += e0;
      z[1][c][r] = e1; s1b += e1;
    }
  }
  s1a += __shfl_xor(s1a, 16); s1a += __shfl_xor(s1a, 32);
  s1b += __shfl_xor(s1b, 16); s1b += __shfl_xor(s1b, 32);
  if (lg == 0) {
    red[w][lr] = s1a;
    red[w][16 + lr] = s1b;
  }
  // ---- prefetch Ext: issued before the barrier, consumed after ----
  f32x4 ex[2][8];
#pragma unroll
  for (int c = 0; c < 8; ++c) {
    const int cb = n0w + c * 16 + lg * 4;
    ex[0][c] = *(const f32x4*)&Ep[(size_t)lr * 512 + cb];
    ex[1][c] = *(const f32x4*)&Ep[(size_t)(16 + lr) * 512 + cb];
  }
  __builtin_amdgcn_sched_barrier(0);
  __syncthreads();
  float l1i[2];
#pragma unroll
  for (int rg = 0; rg < 2; ++rg) {
    const int lrow = rg * 16 + lr;
    l1i[rg] = 1.0f / (red[0][lrow] + red[1][lrow] + red[2][lrow] + red[3][lrow]);
  }
  // ---- pass2: y = w_mn + Ext; e2 = exp(y); sum ----
  float s2a = 0.f, s2b = 0.f;
#pragma unroll
  for (int c = 0; c < 8; ++c)
#pragma unroll
    for (int r = 0; r < 4; ++r) {
      float e0 = __expf(z[0][c][r] * l1i[0] + ex[0][c][r]);
      float e1 = __expf(z[1][c][r] * l1i[1] + ex[1][c][r]);
      z[0][c][r] = e0; s2a += e0;
      z[1][c][r] = e1; s2b += e1;
    }
  s2a += __shfl_xor(s2a, 16); s2a += __shfl_xor(s2a, 32);
  s2b += __shfl_xor(s2b, 16); s2b += __shfl_xor(s2b, 32);
  if (lg == 0) {
    red2[w][lr] = s2a;
    red2[w][16 + lr] = s2b;
  }
  __syncthreads();
  float l2i[2];
#pragma unroll
  for (int rg = 0; rg < 2; ++rg) {
    const int lrow = rg * 16 + lr;
    l2i[rg] = 1.0f / (red2[0][lrow] + red2[1][lrow] + red2[2][lrow] + red2[3][lrow]);
  }
  // ---- P (normalized, bf16) -> per-wave LDS tile [32][144] ----
  unsigned short(*Pw)[144] = (unsigned short(*)[144])wsh[w];
#pragma unroll
  for (int rg = 0; rg < 2; ++rg)
#pragma unroll
    for (int c = 0; c < 8; ++c) {
      ushort4 o;
      o.x = f2bf(z[rg][c][0] * l2i[rg]);
      o.y = f2bf(z[rg][c][1] * l2i[rg]);
      o.z = f2bf(z[rg][c][2] * l2i[rg]);
      o.w = f2bf(z[rg][c][3] * l2i[rg]);
      *(ushort4*)&Pw[rg * 16 + lr][c * 16 + lg * 4] = o;
    }
  // own-wave LDS region: same-wave ds ordering, no barrier needed
  // ---- PV: wave's partial over its 128 keys ----
  f32x4 o[2][4] = {};
#pragma unroll
  for (int kc = 0; kc < 4; ++kc) {
    short8 pa0 = *(const short8*)&Pw[lr][kc * 32 + lg * 8];
    short8 pa1 = *(const short8*)&Pw[16 + lr][kc * 32 + lg * 8];
#pragma unroll
    for (int c2 = 0; c2 < 4; ++c2) {
      short8 vf = *(const short8*)&Vt[(size_t)(c2 * 16 + lr) * 512 + n0w + kc * 32 + lg * 8];
      o[0][c2] = __builtin_amdgcn_mfma_f32_16x16x32_bf16(pa0, vf, o[0][c2], 0, 0, 0);
      o[1][c2] = __builtin_amdgcn_mfma_f32_16x16x32_bf16(pa1, vf, o[1][c2], 0, 0, 0);
    }
  }
  // partial out -> own region (aliases P tile; own-wave only)
  float* ow = (float*)wsh[w];
#pragma unroll
  for (int rg = 0; rg < 2; ++rg)
#pragma unroll
    for (int c2 = 0; c2 < 4; ++c2)
#pragma unroll
      for (int r = 0; r < 4; ++r)
        ow[(rg * 16 + lg * 4 + r) * 68 + c2 * 16 + lr] = o[rg][c2][r];
  __syncthreads();
  // cross-wave sum + vectorized store (ushort4)
#pragma unroll
  for (int i = 0; i < 2; ++i) {
    const int lrow = i * 16 + (t >> 4);
    const int d4 = (t & 15) * 4;
    f32x4 s = *(const f32x4*)&((const float*)wsh[0])[lrow * 68 + d4];
#pragma unroll
    for (int w2 = 1; w2 < 4; ++w2) {
      f32x4 p = *(const f32x4*)&((const float*)wsh[w2])[lrow * 68 + d4];
#pragma unroll
      for (int r = 0; r < 4; ++r) s[r] += p[r];
    }
    ushort4 oo;
    oo.x = f2bf(s[0]); oo.y = f2bf(s[1]); oo.z = f2bf(s[2]); oo.w = f2bf(s[3]);
    *(ushort4*)&hidden[(size_t)(b * 512 + q0 + lrow) * 512 + h * 64 + d4] = oo;
  }
}

// ---------------------------------------------------------------- kernel 3
// out = hidden[8192x512]bf16 @ WoT + bo  (fp32 out)
__global__ __launch_bounds__(256) void out_gemm(
    const unsigned short* __restrict__ hidden, const unsigned short* __restrict__ WoT,
    const float* __restrict__ bo, float* __restrict__ out) {
  const int m0 = blockIdx.x * 128, n0 = blockIdx.y * 128;
  __shared__ unsigned short Al[2][128][40];
  __shared__ unsigned short Bl[2][128][40];
  const int t = threadIdx.x;
  const int w = t >> 6, l = t & 63;
  const int lr = l & 15, lg = l >> 4;
  const int wr = (w >> 1) * 64, wc = (w & 1) * 64;
  f32x4 acc[4][4] = {};
  for (int kk = 0; kk < 512; kk += 64) {
    __syncthreads();
    {
      const int colk8 = (t & 7) * 8;
      const int kc2 = colk8 >> 5, kin2 = colk8 & 31;
#pragma unroll
      for (int p = 0; p < 4; ++p) {
        int row = p * 32 + (t >> 3);
        short8 v = *(const short8*)&hidden[(size_t)(m0 + row) * 512 + kk + colk8];
        *(short8*)&Al[kc2][row][kin2] = v;
      }
#pragma unroll
      for (int p = 0; p < 4; ++p) {
        int row = p * 32 + (t >> 3);
        short8 v = *(const short8*)&WoT[(size_t)(n0 + row) * 512 + kk + colk8];
        *(short8*)&Bl[kc2][row][kin2] = v;
      }
    }
    __syncthreads();
#pragma unroll
    for (int kc = 0; kc < 2; ++kc) {
      short8 a[4], b[4];
      const int lk = lg * 8;
#pragma unroll
      for (int i = 0; i < 4; ++i) a[i] = *(const short8*)&Al[kc][wr + i * 16 + lr][lk];
#pragma unroll
      for (int i = 0; i < 4; ++i) b[i] = *(const short8*)&Bl[kc][wc + i * 16 + lr][lk];
#pragma unroll
      for (int i = 0; i < 4; ++i)
#pragma unroll
        for (int j = 0; j < 4; ++j)
          acc[i][j] = __builtin_amdgcn_mfma_f32_16x16x32_bf16(a[i], b[j], acc[i][j], 0, 0, 0);
    }
  }
#pragma unroll
  for (int j = 0; j < 4; ++j) {
    const int col = n0 + wc + j * 16 + lr;
    const float bb = bo[col];
#pragma unroll
    for (int i = 0; i < 4; ++i)
#pragma unroll
      for (int r = 0; r < 4; ++r)
        out[(size_t)(m0 + wr + i * 16 + lg * 4 + r) * 512 + col] = acc[i][j][r] + bb;
  }
}

// ---------------------------------------------------------------- launch
extern "C" void kernel_launch(void* const* d_in, const int* in_sizes, int n_in,
                              void* d_out, int out_size, void* d_ws, size_t ws_size,
                              hipStream_t stream) {
  const float* queries = (const float*)d_in[0];
  const float* keys = (const float*)d_in[1];
  const float* values = (const float*)d_in[2];
  const float* box = (const float*)d_in[3];
  const float* ext = (const float*)d_in[4];
  const float* Wq = (const float*)d_in[5];
  const float* bq = (const float*)d_in[6];
  const float* Wk = (const float*)d_in[7];
  const float* bk = (const float*)d_in[8];
  const float* Wv = (const float*)d_in[9];
  const float* bv = (const float*)d_in[10];
  const float* Wo = (const float*)d_in[11];
  const float* bo = (const float*)d_in[12];
  float* out = (float*)d_out;

  char* ws = (char*)d_ws;
  unsigned short* q_ws = (unsigned short*)(ws);
  unsigned short* k_ws = (unsigned short*)(ws + 8u * 1024 * 1024);
  unsigned short* vt_ws = (unsigned short*)(ws + 16u * 1024 * 1024);
  unsigned short* hidden = (unsigned short*)(ws + 24u * 1024 * 1024);
  unsigned short* wt = (unsigned short*)(ws + 32u * 1024 * 1024);  // 4 x 512KB

  wprep<<<dim3(8, 8, 4), 256, 0, stream>>>(Wq, Wk, Wv, Wo, wt);
  qkv_gemm<<<dim3(64, 4, 3), 256, 0, stream>>>(queries, keys, values, wt, bq, bk, bv,
                                               q_ws, k_ws, vt_ws);
  attn_kernel<<<dim3(16, 128), 256, 0, stream>>>(q_ws, k_ws, vt_ws, box, ext, hidden);
  out_gemm<<<dim3(64, 4), 256, 0, stream>>>(hidden, wt + 3u * 512 * 512, bo, out);
}